// Round 15
// baseline (316.565 us; speedup 1.0000x reference)
//
#include <hip/hip_runtime.h>

#define B_   8
#define C_   96
#define H_   160
#define W_   320
#define ND   9
#define NDD  81
#define TH   16
#define TW   32
#define F2STRIDE 44                 // 40 payload cols + 4 pad; start-quad (11r+2m)%8 uniform
#define F2PLANE (16*F2STRIDE)       // 704 dw: 16 rows (single dh) per channel
#define NBUF 4
#define LDSWORDS (NBUF*F2PLANE)     // 2816 dw = 11264 B -> 14 blocks/CU

#define AS1 __attribute__((address_space(1)))
#define AS3 __attribute__((address_space(3)))

__device__ __forceinline__ void gld16(const float* gp, float* lp) {
    // HBM/L2 -> LDS direct; LDS dest = wave-uniform base + lane*16
    __builtin_amdgcn_global_load_lds((const AS1 float*)gp,
                                     (AS3 float*)(unsigned long long)lp, 16, 0, 0);
}

__global__ __launch_bounds__(64, 2)
void corr_kernel(const float* __restrict__ f1g,
                 const float* __restrict__ f2g,
                 float* __restrict__ out)
{
    __shared__ float lds[LDSWORDS];

    const int lane = threadIdx.x;       // single wave per block: NO barriers anywhere
    const int r    = lane >> 2;         // 0..15 output row
    const int colb = (lane & 3) << 3;   // 0,8,16,24: 8 px per thread

    // 7200 blocks = 8 XCDs x 900; XCD owns batch b; a tile's 9 dh-waves are
    // dispatch-adjacent (f1 tile + f2 halo L2 reuse).
    const int bid  = blockIdx.x;
    const int ebid = (bid & 7) * 900 + (bid >> 3);
    const int b    = ebid / 900;
    const int rem  = ebid - b * 900;
    const int tile = rem / 9;
    const int dh   = rem - tile * 9;    // this wave's dh
    const int by = tile / 10, bx = tile - by * 10;
    const int x0 = bx * TW, y0 = by * TH;
    const int HWi = H_ * W_;
    const int r0  = y0 + dh - 4;        // first (and only) 16-row f2 slab for this dh

    const float* f1b = f1g + (size_t)b * C_ * HWi;
    const float* f2b = f2g + (size_t)b * C_ * HWi;
    const float* f1p = f1b + (y0 + r) * W_ + x0 + colb;

    // staging descriptors: 176 16B segments (16 rows x 11; col4==10 is pad).
    // seg s -> lds dw 4s; sr = s/11, c4 = s%11; gy = r0+sr, gx = x0-4+4*c4.
    // Halo x-offset (4) == segment width -> gx in [0, W-4] exact.
    int so0, so1, so2; bool pp0, pp1, pp2;
    {
        int s, sr, c4, gy, gx;
        s = lane;       sr = s / 11; c4 = s - 11 * sr; gy = r0 + sr; gx = x0 - 4 + (c4 << 2);
        pp0 = (c4 < 10) & (gy >= 0) & (gy < H_) & (gx >= 0) & (gx <= W_ - 4);
        so0 = gy * W_ + gx;
        s = 64 + lane;  sr = s / 11; c4 = s - 11 * sr; gy = r0 + sr; gx = x0 - 4 + (c4 << 2);
        pp1 = (c4 < 10) & (gy >= 0) & (gy < H_) & (gx >= 0) & (gx <= W_ - 4);
        so1 = gy * W_ + gx;
        s = 128 + lane; sr = s / 11; c4 = s - 11 * sr; gy = r0 + sr; gx = x0 - 4 + (c4 << 2);
        pp2 = (s < 176) & (c4 < 10) & (gy >= 0) & (gy < H_) & (gx >= 0) & (gx <= W_ - 4);
        so2 = gy * W_ + gx;
    }

    const int o0 = r * F2STRIDE + colb;  // compute-side read base (dw)

    // stage channel c into buffer c&3: exactly 3 gld16 (each always has >=1
    // active lane -> always issued -> vmcnt counts are wave-uniform & exact)
    auto stage = [&](int c) {
        const float* g = f2b + c * HWi;
        float* l = &lds[(c & 3) * F2PLANE];
        if (pp0) gld16(g + so0, l);
        if (pp1) gld16(g + so1, l + 256);
        if (pp2) gld16(g + so2, l + 512);
    };

    // ---- accumulators: 9 dw offsets x 8 px ----
    float4 accA0, accA1, accA2, accA3, accA4, accA5, accA6, accA7, accA8;
    float4 accB0, accB1, accB2, accB3, accB4, accB5, accB6, accB7, accB8;
    accA0=accA1=accA2=accA3=accA4=accA5=accA6=accA7=accA8 = make_float4(0.f,0.f,0.f,0.f);
    accB0=accB1=accB2=accB3=accB4=accB5=accB6=accB7=accB8 = make_float4(0.f,0.f,0.f,0.f);
    float4 PAe, PBe, PAo, PBo;          // f1 ping-pong (even/odd channel)

#define F1E(c) { PAe = *(const float4*)(f1p + (c) * HWi);        \
                 PBe = *(const float4*)(f1p + (c) * HWi + 4); }
#define F1O(c) { PAo = *(const float4*)(f1p + (c) * HWi);        \
                 PBo = *(const float4*)(f1p + (c) * HWi + 4); }

#define STEPD(A, P, e0, e1, e2, e3)                          \
        A.x = fmaf(P.x, e0, A.x);                            \
        A.y = fmaf(P.y, e1, A.y);                            \
        A.z = fmaf(P.z, e2, A.z);                            \
        A.w = fmaf(P.w, e3, A.w);

#define COMPUTE(k, PA, PB) {                                                      \
        const int rb_ = ((k) & 3) * F2PLANE;                                      \
        const float4 q0 = *(const float4*)&lds[rb_ + o0];                         \
        const float4 q1 = *(const float4*)&lds[rb_ + o0 + 4];                     \
        const float4 q2 = *(const float4*)&lds[rb_ + o0 + 8];                     \
        const float4 q3 = *(const float4*)&lds[rb_ + o0 + 12];                    \
        const float w[16] = {q0.x,q0.y,q0.z,q0.w,q1.x,q1.y,q1.z,q1.w,            \
                             q2.x,q2.y,q2.z,q2.w,q3.x,q3.y,q3.z,q3.w};           \
        STEPD(accA0, PA, w[0], w[1], w[2], w[3])                                  \
        STEPD(accB0, PB, w[4], w[5], w[6], w[7])                                  \
        STEPD(accA1, PA, w[1], w[2], w[3], w[4])                                  \
        STEPD(accB1, PB, w[5], w[6], w[7], w[8])                                  \
        STEPD(accA2, PA, w[2], w[3], w[4], w[5])                                  \
        STEPD(accB2, PB, w[6], w[7], w[8], w[9])                                  \
        STEPD(accA3, PA, w[3], w[4], w[5], w[6])                                  \
        STEPD(accB3, PB, w[7], w[8], w[9], w[10])                                 \
        STEPD(accA4, PA, w[4], w[5], w[6], w[7])                                  \
        STEPD(accB4, PB, w[8], w[9], w[10], w[11])                                \
        STEPD(accA5, PA, w[5], w[6], w[7], w[8])                                  \
        STEPD(accB5, PB, w[9], w[10], w[11], w[12])                               \
        STEPD(accA6, PA, w[6], w[7], w[8], w[9])                                  \
        STEPD(accB6, PB, w[10], w[11], w[12], w[13])                              \
        STEPD(accA7, PA, w[7], w[8], w[9], w[10])                                 \
        STEPD(accB7, PB, w[11], w[12], w[13], w[14])                              \
        STEPD(accA8, PA, w[8], w[9], w[10], w[11])                                \
        STEPD(accB8, PB, w[12], w[13], w[14], w[15])                              \
    }

#define WAITV(n) { asm volatile("s_waitcnt vmcnt(" #n ")" ::: "memory");  \
                   __builtin_amdgcn_sched_barrier(0); }

    // one-time zero: OOB/pad slots are never DMA'd (channel-invariant mask)
    // and payload is rewritten on every buffer reuse -> zeros persist.
    for (int t = lane; t < LDSWORDS; t += 64) lds[t] = 0.f;
    asm volatile("s_waitcnt lgkmcnt(0)" ::: "memory");

    // prologue (interleaved so in-order vmcnt retirement matches steady state)
    stage(0); F1E(0); stage(1); F1O(1); stage(2);

    // steady state at wait(k): outstanding = S(k+2)[3] + F1(k+1)[2] = 5
#define BODY(k, PA, PB, F1M)                          \
    WAITV(5)                                          \
    COMPUTE(k, PA, PB)                                \
    if ((k) + 3 < C_) stage((k) + 3);                 \
    F1M((k) + 2);

#pragma unroll 1
    for (int j = 0; j < 47; ++j) {       // k = 0..93
        const int k = 2 * j;
        BODY(k,     PAe, PBe, F1E)
        BODY(k + 1, PAo, PBo, F1O)
    }
    // peeled tail: k=94 (outstanding after F1(94) = F1(95) only), k=95
    WAITV(2) COMPUTE(94, PAe, PBe)
    WAITV(0) COMPUTE(95, PAo, PBo)

    // ---- epilogue: out[b, dh*9+d, y0+r, x0+colb..+7] ----
    const int gy = y0 + r;
    const int gx = x0 + colb;
#define STORED(d) {                                                                 \
        float* op_ = out + (size_t)((b * NDD + dh * ND + d) * H_ + gy) * W_ + gx;   \
        *(float4*)op_ = accA##d;                                                    \
        *(float4*)(op_ + 4) = accB##d; }
    STORED(0) STORED(1) STORED(2) STORED(3) STORED(4)
    STORED(5) STORED(6) STORED(7) STORED(8)
}

extern "C" void kernel_launch(void* const* d_in, const int* in_sizes, int n_in,
                              void* d_out, int out_size, void* d_ws, size_t ws_size,
                              hipStream_t stream)
{
    const float* f1 = (const float*)d_in[0];
    const float* f2 = (const float*)d_in[1];
    float* out = (float*)d_out;
    corr_kernel<<<dim3(7200), 64, 0, stream>>>(f1, f2, out);
}

// Round 17
// 250.444 us; speedup vs baseline: 1.2640x; 1.2640x over previous
//
#include <hip/hip_runtime.h>

#define B_   8
#define C_   96
#define H_   160
#define W_   320
#define ND   9
#define NDD  81
#define TH   16
#define TW   32                 // 8 px/thread
#define KC   6                  // channels per chunk = 3 h2-packs; wave w owns pack w
#define NCH  16
#define F2ROWS 18
#define F2STRIDE 44             // dw(=h2) per row: 40 payload + 4 pad; 44rW%4==0 (b128-aligned)
#define F2PLANE (F2ROWS*F2STRIDE)   // 792 dw per 2-channel pack
#define BUFW (3*F2PLANE)            // 2376 dw per buffer (3 packs)
// payload 2*BUFW = 4752 dw = 19008 B; padded to 36 KB -> 4 blocks/CU ->
// allocator target 3 waves/EU -> ~170-reg cap (validated model, R9-R14).
#define LDSWORDS 9216               // 36864 B

using h2 = __fp16 __attribute__((ext_vector_type(2)));   // matches builtin types
__device__ __forceinline__ float bcf(h2 x) { return __builtin_bit_cast(float, x); }
__device__ __forceinline__ h2    bch(float x) { return __builtin_bit_cast(h2, x); }
#define CVT(a, b) __builtin_amdgcn_cvt_pkrtz((a), (b))

__global__ __launch_bounds__(192, 2)
void corr_kernel(const float* __restrict__ f1g,
                 const float* __restrict__ f2g,
                 float* __restrict__ out)
{
    __shared__ float lds[LDSWORDS];

    const int tid  = threadIdx.x;
    const int wave = tid >> 6;          // dh-within-group AND staging pack index
    const int lane = tid & 63;
    const int row  = lane >> 2;         // 0..15
    const int colb = (lane & 3) << 3;   // 0,8,16,24

    // XCD swizzle: 2400 = 8 XCDs x 300 (bijective); XCD owns batch b.
    const int bid  = blockIdx.x;
    const int ebid = (bid & 7) * 300 + (bid >> 3);
    const int b    = ebid / 300;
    const int t3   = ebid - b * 300;
    const int g    = t3 % 3;            // dh = 3g + wave
    const int tile = t3 / 3;
    const int by   = tile / 10, bx = tile - by * 10;
    const int x0 = bx * TW, y0 = by * TH;
    const int HWi  = H_ * W_;
    const int r0   = y0 + 3 * g - 4;

    const float* f1b = f1g + (size_t)b * C_ * HWi;
    const float* f2b = f2g + (size_t)b * C_ * HWi;
    const float* f1p = f1b + (y0 + row) * W_ + x0 + colb;

    // ---- staging descriptors: pack plane = 18 rows x 10 f4-segments ----
    // seg s: row=s/10, c4=s%10, gx = x0-4+4c4 (16B-aligned; offset-4 == seg
    // width -> fully in or fully out: gx in [0,W-4] exact). 180 segs:
    // round t covers s = 64t+lane (round 2: lane<52).
    int so0, so1, so2, lo0, lo1, lo2;
    bool pd0, pd1, pd2, wr2;
    {
        int s, r, c4, gy, gx;
        s = lane;       r = s / 10; c4 = s - 10 * r; gy = r0 + r; gx = x0 - 4 + (c4 << 2);
        pd0 = (gy >= 0) & (gy < H_) & (gx >= 0) & (gx <= W_ - 4);
        so0 = gy * W_ + gx; lo0 = r * F2STRIDE + (c4 << 2);
        s = 64 + lane;  r = s / 10; c4 = s - 10 * r; gy = r0 + r; gx = x0 - 4 + (c4 << 2);
        pd1 = (gy >= 0) & (gy < H_) & (gx >= 0) & (gx <= W_ - 4);
        so1 = gy * W_ + gx; lo1 = r * F2STRIDE + (c4 << 2);
        s = 128 + lane; r = s / 10; c4 = s - 10 * r; gy = r0 + r; gx = x0 - 4 + (c4 << 2);
        wr2 = (lane < 52);
        pd2 = wr2 & (gy >= 0) & (gy < H_) & (gx >= 0) & (gx <= W_ - 4);
        so2 = gy * W_ + gx; lo2 = r * F2STRIDE + (c4 << 2);
    }
    const int wofs = wave * F2PLANE;    // own pack's plane base (dw)
    const int o0   = (row + wave) * F2STRIDE + colb;   // compute read base

    const float4 z4 = make_float4(0.f, 0.f, 0.f, 0.f);
    float4 sA0, sB0, sA1, sB1, sA2, sB2;       // staging regs (one pack in flight)

    // issue-early: 6 global f4 loads for pack `wave` of chunk cb
#define SLOAD(cb) {                                                     \
        const int ca_ = (cb) + 2 * wave;                                \
        const float* pa_ = f2b + ca_ * HWi;                             \
        const float* pb_ = f2b + (ca_ + 1) * HWi;                       \
        sA0 = pd0 ? *(const float4*)(pa_ + so0) : z4;                   \
        sB0 = pd0 ? *(const float4*)(pb_ + so0) : z4;                   \
        sA1 = pd1 ? *(const float4*)(pa_ + so1) : z4;                   \
        sB1 = pd1 ? *(const float4*)(pb_ + so1) : z4;                   \
        sA2 = pd2 ? *(const float4*)(pa_ + so2) : z4;                   \
        sB2 = pd2 ? *(const float4*)(pb_ + so2) : z4; }

    // write-late: cvt to packed f16 (ch c -> lo, c+1 -> hi) + 3 ds_write_b128
#define SWRITE(bufb) {                                                  \
        float4 o_;                                                      \
        o_.x = bcf(CVT(sA0.x, sB0.x)); o_.y = bcf(CVT(sA0.y, sB0.y));   \
        o_.z = bcf(CVT(sA0.z, sB0.z)); o_.w = bcf(CVT(sA0.w, sB0.w));   \
        *(float4*)&lds[(bufb) + wofs + lo0] = o_;                       \
        o_.x = bcf(CVT(sA1.x, sB1.x)); o_.y = bcf(CVT(sA1.y, sB1.y));   \
        o_.z = bcf(CVT(sA1.z, sB1.z)); o_.w = bcf(CVT(sA1.w, sB1.w));   \
        *(float4*)&lds[(bufb) + wofs + lo1] = o_;                       \
        if (wr2) {                                                      \
            o_.x = bcf(CVT(sA2.x, sB2.x)); o_.y = bcf(CVT(sA2.y, sB2.y)); \
            o_.z = bcf(CVT(sA2.z, sB2.z)); o_.w = bcf(CVT(sA2.w, sB2.w)); \
            *(float4*)&lds[(bufb) + wofs + lo2] = o_;                   \
        } }

    // ---- f1 packed regs: 3 packs x 8 h2 ----
    h2 hA0, hA1, hA2, hA3, hA4, hA5, hA6, hA7;
    h2 hB0, hB1, hB2, hB3, hB4, hB5, hB6, hB7;
    h2 hC0, hC1, hC2, hC3, hC4, hC5, hC6, hC7;

#define F1PACK(P, ca) {                                                 \
        const float4 a0 = *(const float4*)(f1p + (ca) * HWi);           \
        const float4 a1 = *(const float4*)(f1p + (ca) * HWi + 4);       \
        const float4 b0 = *(const float4*)(f1p + ((ca) + 1) * HWi);     \
        const float4 b1 = *(const float4*)(f1p + ((ca) + 1) * HWi + 4); \
        h##P##0 = CVT(a0.x, b0.x); h##P##1 = CVT(a0.y, b0.y);           \
        h##P##2 = CVT(a0.z, b0.z); h##P##3 = CVT(a0.w, b0.w);           \
        h##P##4 = CVT(a1.x, b1.x); h##P##5 = CVT(a1.y, b1.y);           \
        h##P##6 = CVT(a1.z, b1.z); h##P##7 = CVT(a1.w, b1.w); }

    // ---- accumulators: 9 offsets x 8 px ----
    float4 accA0, accA1, accA2, accA3, accA4, accA5, accA6, accA7, accA8;
    float4 accB0, accB1, accB2, accB3, accB4, accB5, accB6, accB7, accB8;
    accA0=accA1=accA2=accA3=accA4=accA5=accA6=accA7=accA8 = z4;
    accB0=accB1=accB2=accB3=accB4=accB5=accB6=accB7=accB8 = z4;

#define DOT(A, G, U) A = __builtin_amdgcn_fdot2((G), (U), (A), false);
#define DROW(AD, BD, ua, ub, uc, ud, ue, uf, ug, uh)                    \
        DOT(AD.x, G0, ua) DOT(AD.y, G1, ub) DOT(AD.z, G2, uc) DOT(AD.w, G3, ud) \
        DOT(BD.x, G4, ue) DOT(BD.y, G5, uf) DOT(BD.z, G6, ug) DOT(BD.w, G7, uh)

#define COMPP(BASE, P0,P1,P2,P3,P4,P5,P6,P7) {                          \
        const float4 q0 = *(const float4*)&lds[(BASE)];                 \
        const float4 q1 = *(const float4*)&lds[(BASE) + 4];             \
        const float4 q2 = *(const float4*)&lds[(BASE) + 8];             \
        const float4 q3 = *(const float4*)&lds[(BASE) + 12];            \
        const h2 G0=(P0),G1=(P1),G2=(P2),G3=(P3),G4=(P4),G5=(P5),G6=(P6),G7=(P7); \
        const h2 u0=bch(q0.x),u1=bch(q0.y),u2=bch(q0.z),u3=bch(q0.w);   \
        const h2 u4=bch(q1.x),u5=bch(q1.y),u6=bch(q1.z),u7=bch(q1.w);   \
        const h2 u8=bch(q2.x),u9=bch(q2.y),u10=bch(q2.z),u11=bch(q2.w); \
        const h2 u12=bch(q3.x),u13=bch(q3.y),u14=bch(q3.z),u15=bch(q3.w);\
        DROW(accA0, accB0, u0,u1,u2,u3,   u4,u5,u6,u7)                  \
        DROW(accA1, accB1, u1,u2,u3,u4,   u5,u6,u7,u8)                  \
        DROW(accA2, accB2, u2,u3,u4,u5,   u6,u7,u8,u9)                  \
        DROW(accA3, accB3, u3,u4,u5,u6,   u7,u8,u9,u10)                 \
        DROW(accA4, accB4, u4,u5,u6,u7,   u8,u9,u10,u11)                \
        DROW(accA5, accB5, u5,u6,u7,u8,   u9,u10,u11,u12)               \
        DROW(accA6, accB6, u6,u7,u8,u9,   u10,u11,u12,u13)              \
        DROW(accA7, accB7, u7,u8,u9,u10,  u11,u12,u13,u14)              \
        DROW(accA8, accB8, u8,u9,u10,u11, u12,u13,u14,u15)              \
    }

    // ---- prologue: chunk 0 staged into buf 0 ----
    SLOAD(0)
    SWRITE(0)

#pragma unroll 1
    for (int k = 0; k < NCH; ++k) {
        __syncthreads();                       // buf-k writes visible to all waves
        const int cb = KC * k;
        F1PACK(A, cb) F1PACK(B, cb + 2) F1PACK(C, cb + 4)
        if (k + 1 < NCH) SLOAD(KC * (k + 1))   // issue-early (T14)
        __builtin_amdgcn_sched_barrier(0);
        const int rb = (k & 1) * BUFW;
        COMPP(rb + o0,               hA0,hA1,hA2,hA3,hA4,hA5,hA6,hA7)
        COMPP(rb + F2PLANE + o0,     hB0,hB1,hB2,hB3,hB4,hB5,hB6,hB7)
        COMPP(rb + 2*F2PLANE + o0,   hC0,hC1,hC2,hC3,hC4,hC5,hC6,hC7)
        if (k + 1 < NCH) SWRITE(((k + 1) & 1) * BUFW)   // write-late
    }

    // ---- epilogue: dh = 3g + wave; out[b, dh*9+d, y0+row, x0+colb..+7] ----
    const int dh = 3 * g + wave;
    const int gy = y0 + row;
    const int gx = x0 + colb;
#define STORED(d) {                                                                 \
        float* op_ = out + (size_t)((b * NDD + dh * ND + d) * H_ + gy) * W_ + gx;   \
        *(float4*)op_ = accA##d;                                                    \
        *(float4*)(op_ + 4) = accB##d; }
    STORED(0) STORED(1) STORED(2) STORED(3) STORED(4)
    STORED(5) STORED(6) STORED(7) STORED(8)
}

extern "C" void kernel_launch(void* const* d_in, const int* in_sizes, int n_in,
                              void* d_out, int out_size, void* d_ws, size_t ws_size,
                              hipStream_t stream)
{
    const float* f1 = (const float*)d_in[0];
    const float* f2 = (const float*)d_in[1];
    float* out = (float*)d_out;
    corr_kernel<<<dim3(2400), 192, 0, stream>>>(f1, f2, out);
}

// Round 18
// 249.169 us; speedup vs baseline: 1.2705x; 1.0051x over previous
//
#include <hip/hip_runtime.h>

#define B_   8
#define C_   96
#define H_   160
#define W_   320
#define ND   9
#define NDD  81
#define TH   16
#define TW   32                 // 8 px/thread
#define KC   4                  // channels per chunk
#define NCH  24
#define F2ROWS 18
#define F2STRIDE 44             // 40 payload + 4 pad cols
#define F2PLANE (F2ROWS*F2STRIDE)   // 792 dw per channel
#define BUFW (KC*F2PLANE)           // 3168 dw = 12672 B
// payload 2*BUFW = 25344 B; padded to 32 KB -> 5 blocks/CU -> allocator
// target 4 waves/EU -> 128-reg budget > ~110 demand (ping-pong P set).
#define LDSWORDS 8192               // 32768 B

#define AS1 __attribute__((address_space(1)))
#define AS3 __attribute__((address_space(3)))

__device__ __forceinline__ void gld16(const float* gp, float* lp) {
    __builtin_amdgcn_global_load_lds((const AS1 float*)gp,
                                     (AS3 float*)(unsigned long long)lp, 16, 0, 0);
}

__global__ __launch_bounds__(192, 2)
void corr_kernel(const float* __restrict__ f1g,
                 const float* __restrict__ f2g,
                 float* __restrict__ out)
{
    __shared__ float lds[LDSWORDS];

    const int tid  = threadIdx.x;
    const int wave = tid >> 6;
    const int lane = tid & 63;
    const int row  = lane >> 2;         // 0..15
    const int colb = (lane & 3) << 3;   // 0,8,16,24

    const int bid  = blockIdx.x;
    const int ebid = (bid & 7) * 300 + (bid >> 3);
    const int b    = ebid / 300;
    const int t3   = ebid - b * 300;
    const int g    = t3 % 3;            // dh = 3g + wave
    const int tile = t3 / 3;
    const int by   = tile / 10, bx = tile - by * 10;
    const int x0 = bx * TW, y0 = by * TH;
    const int HWi  = H_ * W_;
    const int r0   = y0 + 3 * g - 4;

    const float* f1b = f1g + (size_t)b * C_ * HWi;
    const float* f2b = f2g + (size_t)b * C_ * HWi;
    const float* f1p = f1b + (y0 + row) * W_ + x0 + colb;

    // f2 staging maps (seg s -> lds dw 4s; r=s/11, c4=s%11; c4==10 = pad col)
    int soW, soT; bool ppW, ppT;
    {
        int s  = (wave << 6) + lane;
        int r  = s / 11, c4 = s - 11 * r;
        int gy = r0 + r, gx = x0 - 4 + (c4 << 2);
        ppW = (c4 < 10) & (gy >= 0) & (gy < H_) & (gx >= 0) & (gx <= W_ - 4);
        soW = gy * W_ + gx;
        s  = 192 + lane;
        r  = s / 11; c4 = s - 11 * r;
        gy = r0 + r; gx = x0 - 4 + (c4 << 2);
        ppT = (wave == 2) & (lane < 6) & (c4 < 10) &
              (gy >= 0) & (gy < H_) & (gx >= 0) & (gx <= W_ - 4);
        soT = gy * W_ + gx;
    }
    const int partoff = wave << 8;

    const int o0 = (row + wave) * F2STRIDE + colb;

    auto stage = [&](int cb, int bufb) {
#pragma unroll
        for (int c = 0; c < KC; ++c) {
            const float* gsrc = f2b + (cb + c) * HWi;
            float* l = &lds[bufb + c * F2PLANE];
            if (ppW) gld16(gsrc + soW, l + partoff);
            if (ppT) gld16(gsrc + soT, l + 768);
        }
    };

    // ---- accumulators ----
    float4 accA0, accA1, accA2, accA3, accA4, accA5, accA6, accA7, accA8;
    float4 accB0, accB1, accB2, accB3, accB4, accB5, accB6, accB7, accB8;
    accA0=accA1=accA2=accA3=accA4=accA5=accA6=accA7=accA8 = make_float4(0.f,0.f,0.f,0.f);
    accB0=accB1=accB2=accB3=accB4=accB5=accB6=accB7=accB8 = make_float4(0.f,0.f,0.f,0.f);

    // f1 ping-pong register sets (named; rule 20)
    float4 PAe0, PAe1, PAe2, PAe3, PBe0, PBe1, PBe2, PBe3;   // even chunks
    float4 PAo0, PAo1, PAo2, PAo3, PBo0, PBo1, PBo2, PBo3;   // odd chunks

#define F1LOADE(cb) {                                             \
        PAe0 = *(const float4*)(f1p + (cb) * HWi);                \
        PBe0 = *(const float4*)(f1p + (cb) * HWi + 4);            \
        PAe1 = *(const float4*)(f1p + ((cb)+1) * HWi);            \
        PBe1 = *(const float4*)(f1p + ((cb)+1) * HWi + 4);        \
        PAe2 = *(const float4*)(f1p + ((cb)+2) * HWi);            \
        PBe2 = *(const float4*)(f1p + ((cb)+2) * HWi + 4);        \
        PAe3 = *(const float4*)(f1p + ((cb)+3) * HWi);            \
        PBe3 = *(const float4*)(f1p + ((cb)+3) * HWi + 4); }
#define F1LOADO(cb) {                                             \
        PAo0 = *(const float4*)(f1p + (cb) * HWi);                \
        PBo0 = *(const float4*)(f1p + (cb) * HWi + 4);            \
        PAo1 = *(const float4*)(f1p + ((cb)+1) * HWi);            \
        PBo1 = *(const float4*)(f1p + ((cb)+1) * HWi + 4);        \
        PAo2 = *(const float4*)(f1p + ((cb)+2) * HWi);            \
        PBo2 = *(const float4*)(f1p + ((cb)+2) * HWi + 4);        \
        PAo3 = *(const float4*)(f1p + ((cb)+3) * HWi);            \
        PBo3 = *(const float4*)(f1p + ((cb)+3) * HWi + 4); }

#define STEPD(A, P, e0, e1, e2, e3)                          \
        A.x = fmaf(P.x, e0, A.x);                            \
        A.y = fmaf(P.y, e1, A.y);                            \
        A.z = fmaf(P.z, e2, A.z);                            \
        A.w = fmaf(P.w, e3, A.w);

#define COMPC(c, RB, PA, PB) {                                                    \
        const float4 q0 = *(const float4*)&lds[(RB) + c * F2PLANE + o0];          \
        const float4 q1 = *(const float4*)&lds[(RB) + c * F2PLANE + o0 + 4];      \
        const float4 q2 = *(const float4*)&lds[(RB) + c * F2PLANE + o0 + 8];      \
        const float4 q3 = *(const float4*)&lds[(RB) + c * F2PLANE + o0 + 12];     \
        const float w[16] = {q0.x,q0.y,q0.z,q0.w,q1.x,q1.y,q1.z,q1.w,            \
                             q2.x,q2.y,q2.z,q2.w,q3.x,q3.y,q3.z,q3.w};           \
        STEPD(accA0, PA, w[0], w[1], w[2], w[3])                                  \
        STEPD(accB0, PB, w[4], w[5], w[6], w[7])                                  \
        STEPD(accA1, PA, w[1], w[2], w[3], w[4])                                  \
        STEPD(accB1, PB, w[5], w[6], w[7], w[8])                                  \
        STEPD(accA2, PA, w[2], w[3], w[4], w[5])                                  \
        STEPD(accB2, PB, w[6], w[7], w[8], w[9])                                  \
        STEPD(accA3, PA, w[3], w[4], w[5], w[6])                                  \
        STEPD(accB3, PB, w[7], w[8], w[9], w[10])                                 \
        STEPD(accA4, PA, w[4], w[5], w[6], w[7])                                  \
        STEPD(accB4, PB, w[8], w[9], w[10], w[11])                                \
        STEPD(accA5, PA, w[5], w[6], w[7], w[8])                                  \
        STEPD(accB5, PB, w[9], w[10], w[11], w[12])                               \
        STEPD(accA6, PA, w[6], w[7], w[8], w[9])                                  \
        STEPD(accB6, PB, w[10], w[11], w[12], w[13])                              \
        STEPD(accA7, PA, w[7], w[8], w[9], w[10])                                 \
        STEPD(accB7, PB, w[11], w[12], w[13], w[14])                              \
        STEPD(accA8, PA, w[8], w[9], w[10], w[11])                                \
        STEPD(accB8, PB, w[12], w[13], w[14], w[15])                              \
    }
#define CHUNKE(RB) COMPC(0,RB,PAe0,PBe0) COMPC(1,RB,PAe1,PBe1) \
                   COMPC(2,RB,PAe2,PBe2) COMPC(3,RB,PAe3,PBe3)
#define CHUNKO(RB) COMPC(0,RB,PAo0,PBo0) COMPC(1,RB,PAo1,PBo1) \
                   COMPC(2,RB,PAo2,PBo2) COMPC(3,RB,PAo3,PBo3)

    // one-time zero (OOB/pad slots never DMA'd; payload rewritten every chunk)
    for (int t = tid; t < LDSWORDS; t += 192) lds[t] = 0.f;
    __syncthreads();

    // prologue: chunk-0 f2 DMA + chunk-0 f1 regs issued one full iter early
    stage(0, 0);
    F1LOADE(0)

    // body(k): syncthreads (drains S(k)+F1(k), both issued 1 iter ago; syncs
    // buffers) -> issue S(k+1)+F1(k+1) -> compute chunk k. The f1 global
    // latency and the DMA latency are both hidden under a full compute phase.
#define BODY(k, CHUNKM, F1M)                                        \
    __syncthreads();                                                \
    if ((k) + 1 < NCH) {                                            \
        stage(KC * ((k) + 1), (((k) + 1) & 1) * BUFW);              \
        F1M(KC * ((k) + 1))                                         \
    }                                                               \
    __builtin_amdgcn_sched_barrier(0);                              \
    CHUNKM(((k) & 1) * BUFW)

#pragma unroll 1
    for (int j = 0; j < NCH / 2; ++j) {
        const int k = 2 * j;
        BODY(k,     CHUNKE, F1LOADO)
        BODY(k + 1, CHUNKO, F1LOADE)
    }

    // ---- epilogue ----
    const int dh = 3 * g + wave;
    const int gy = y0 + row;
    const int gx = x0 + colb;
#define STORED(d) {                                                                 \
        float* op_ = out + (size_t)((b * NDD + dh * ND + d) * H_ + gy) * W_ + gx;   \
        *(float4*)op_ = accA##d;                                                    \
        *(float4*)(op_ + 4) = accB##d; }
    STORED(0) STORED(1) STORED(2) STORED(3) STORED(4)
    STORED(5) STORED(6) STORED(7) STORED(8)
}

extern "C" void kernel_launch(void* const* d_in, const int* in_sizes, int n_in,
                              void* d_out, int out_size, void* d_ws, size_t ws_size,
                              hipStream_t stream)
{
    const float* f1 = (const float*)d_in[0];
    const float* f2 = (const float*)d_in[1];
    float* out = (float*)d_out;
    corr_kernel<<<dim3(2400), 192, 0, stream>>>(f1, f2, out);
}

// Round 19
// 248.121 us; speedup vs baseline: 1.2759x; 1.0042x over previous
//
#include <hip/hip_runtime.h>

#define B_   8
#define C_   96
#define H_   160
#define W_   320
#define ND   9
#define NDD  81
#define HWi_ (H_*W_)
#define TWV  5                  // waves/block = output rows/block
#define F2R  13                 // staged f2 rows (r0 .. r0+12)
#define F2C  24                 // staged f2 cols (x0-4 .. x0+19)
#define C2S  20                 // c2 stride: 16 packs + 4 pad (free bank pattern, b128-aligned)
#define F1P1 1600               // f1 packs per buffer: 5*16*20
#define F2P1 6240               // f2 packs per buffer: 13*24*20
#define F1B  0
#define F2B  3200               // f1 region = 2*1600
#define SCB  3200               // epilogue scratch overlays f2p (needs 6480 dw <= 12480)
#define LDSW 15680              // 62720 B -> 2 blocks/CU -> reg budget >= 170

using h2    = __fp16 __attribute__((ext_vector_type(2)));
using f16x8 = __fp16 __attribute__((ext_vector_type(8)));
using f32x4 = float  __attribute__((ext_vector_type(4)));
__device__ __forceinline__ float bcf(h2 x) { return __builtin_bit_cast(float, x); }
#define CVT(a, b) __builtin_amdgcn_cvt_pkrtz((a), (b))

__global__ __launch_bounds__(320, 2)
void corr_kernel(const float* __restrict__ f1g,
                 const float* __restrict__ f2g,
                 float* __restrict__ out)
{
    __shared__ float lds[LDSW];

    const int tid  = threadIdx.x;
    const int wave = tid >> 6;          // output row h0+wave
    const int lane = tid & 63;
    const int l15  = lane & 15;
    const int lk4  = (lane >> 4) << 2;  // c2-group base within chunk

    // grid 5120 = 8 XCDs x 640; XCD owns batch b; hb sweeps slowest (L2 row reuse)
    const int bid  = blockIdx.x;
    const int ebid = (bid & 7) * 640 + (bid >> 3);
    const int b    = ebid / 640;
    const int t2   = ebid - b * 640;
    const int hb   = t2 / 20, wt = t2 - hb * 20;
    const int h0 = 5 * hb, w0 = 16 * wt;
    const int r0 = h0 - 4;

    const float* f1b = f1g + (size_t)b * C_ * HWi_;
    const float* f2b = f2g + (size_t)b * C_ * HWi_;

    // ---- f2 staging descriptors: 4 units/thread (u = tid+320i), col-fast ----
    const float* f2src[4]; bool pv[4]; int wadr[4];
#pragma unroll
    for (int i = 0; i < 4; ++i) {
        const int u   = tid + 320 * i;
        const int cg  = u % 6;
        const int row = (u / 6) % 13;
        const int c2  = u / 78;
        const int gy  = r0 + row;
        const int gx  = w0 - 4 + 4 * cg;
        pv[i]   = (u < 1248) && (gy >= 0) && (gy < H_) && (gx >= 0) && (gx <= W_ - 4);
        f2src[i] = f2b + (2 * c2) * HWi_ + gy * W_ + gx;
        wadr[i] = (row * F2C + 4 * cg) * C2S + c2;
    }
    // ---- f1 staging: 1 unit/thread ----
    const int fpxg = tid & 3, frow = (tid >> 2) % 5, fc2 = tid / 20;
    const float* f1src = f1b + (2 * fc2) * HWi_ + (h0 + frow) * W_ + w0 + 4 * fpxg;
    const int f1wadr = (frow * 16 + 4 * fpxg) * C2S + fc2;

    // ---- frag read offsets ----
    const int aoff  = (wave * 16 + l15) * C2S + lk4;   // + F1B + buf*F1P1
    const int boffc = l15 * C2S + lk4;                 // + F2B + buf*F2P1 + (wave+dh)*480 + tile*160

    // ---- band-extraction precompute: px=4*(l>>4)+r, c=8*tile+l15, dw=c-px ----
    int voff[2][4]; bool vok[2][4];
#pragma unroll
    for (int t = 0; t < 2; ++t)
#pragma unroll
        for (int r = 0; r < 4; ++r) {
            const int px = (lane >> 4) * 4 + r;
            const int c  = 8 * t + l15;
            const int dw = c - px;
            vok[t][r]  = (dw >= 0) && (dw <= 8) && (t == 0 || l15 >= 8);
            voff[t][r] = dw * 16 + px;
        }

    // ---- staging register sets + lambdas ----
    float4 s2a[4], s2b[4], s1a, s1b;
    auto f2loads = [&](int kap) {
#pragma unroll
        for (int i = 0; i < 4; ++i) if (pv[i]) {
            const float* p = f2src[i] + kap * 32 * HWi_;
            s2a[i] = *(const float4*)p;
            s2b[i] = *(const float4*)(p + HWi_);
        }
    };
    auto f2writes = [&](int wb) {
#pragma unroll
        for (int i = 0; i < 4; ++i) if (pv[i]) {
            const float* pa = (const float*)&s2a[i];
            const float* pb = (const float*)&s2b[i];
#pragma unroll
            for (int j = 0; j < 4; ++j)
                lds[F2B + wb * F2P1 + wadr[i] + j * C2S] = bcf(CVT(pa[j], pb[j]));
        }
    };
    auto f1loads = [&](int kap) {
        const float* p = f1src + kap * 32 * HWi_;
        s1a = *(const float4*)p;
        s1b = *(const float4*)(p + HWi_);
    };
    auto f1writes = [&](int wb) {
        const float* pa = (const float*)&s1a;
        const float* pb = (const float*)&s1b;
#pragma unroll
        for (int j = 0; j < 4; ++j)
            lds[F1B + wb * F1P1 + f1wadr + j * C2S] = bcf(CVT(pa[j], pb[j]));
    };

    // ---- zero f2p (OOB slots never written; valid slots rewritten each chunk) ----
    const float4 z4 = make_float4(0.f, 0.f, 0.f, 0.f);
#pragma unroll
    for (int i = 0; i < 10; ++i) {
        const int u = tid + 320 * i;
        if (u < 3120) *(float4*)&lds[F2B + 4 * u] = z4;
    }
    __syncthreads();

    // ---- prologue: chunk 0 -> buf 0 ----
    f1loads(0); f2loads(0);
    f1writes(0); f2writes(0);
    __syncthreads();

    f32x4 acc[ND][2];
#pragma unroll
    for (int dh = 0; dh < ND; ++dh) { acc[dh][0] = (f32x4)0.f; acc[dh][1] = (f32x4)0.f; }

#pragma unroll
    for (int kap = 0; kap < 3; ++kap) {
        const int rb = kap & 1;
        if (kap < 2) { f1loads(kap + 1); f2loads(kap + 1); }   // issue-early (T14)
        __builtin_amdgcn_sched_barrier(0);
        const f16x8 A = __builtin_bit_cast(f16x8,
            *(const float4*)&lds[F1B + rb * F1P1 + aoff]);
#pragma unroll
        for (int dh = 0; dh < ND; ++dh) {
            const int rbase = F2B + rb * F2P1 + (wave + dh) * (F2C * C2S) + boffc;
            const f16x8 B0 = __builtin_bit_cast(f16x8, *(const float4*)&lds[rbase]);
            const f16x8 B1 = __builtin_bit_cast(f16x8, *(const float4*)&lds[rbase + 8 * C2S]);
            acc[dh][0] = __builtin_amdgcn_mfma_f32_16x16x32_f16(A, B0, acc[dh][0], 0, 0, 0);
            acc[dh][1] = __builtin_amdgcn_mfma_f32_16x16x32_f16(A, B1, acc[dh][1], 0, 0, 0);
        }
        __builtin_amdgcn_sched_barrier(0);
        if (kap < 2) { f1writes(rb ^ 1); f2writes(rb ^ 1); __syncthreads(); }
    }
    __syncthreads();     // all waves done reading LDS before scratch overwrite

    // ---- band extraction -> scratch [wrow][81][16] ----
    const int scw = SCB + wave * 1296;
#pragma unroll
    for (int dh = 0; dh < ND; ++dh)
#pragma unroll
        for (int t = 0; t < 2; ++t)
#pragma unroll
            for (int r = 0; r < 4; ++r)
                if (vok[t][r])
                    lds[scw + dh * 144 + voff[t][r]] = acc[dh][t][r];
    __syncthreads();

    // ---- coalesced readback + store: 1620 f4 units ----
    const size_t ob = (size_t)b * NDD * HWi_;
#pragma unroll
    for (int i = 0; i < 6; ++i) {
        const int u = tid + 320 * i;
        if (u < 1620) {
            const int wrow = u / 324;
            const int rem  = u - wrow * 324;
            const int d    = rem >> 2;
            const int pxg  = rem & 3;
            const float4 v = *(const float4*)&lds[SCB + wrow * 1296 + d * 16 + 4 * pxg];
            *(float4*)&out[ob + (size_t)d * HWi_ + (h0 + wrow) * W_ + w0 + 4 * pxg] = v;
        }
    }
}

extern "C" void kernel_launch(void* const* d_in, const int* in_sizes, int n_in,
                              void* d_out, int out_size, void* d_ws, size_t ws_size,
                              hipStream_t stream)
{
    const float* f1 = (const float*)d_in[0];
    const float* f2 = (const float*)d_in[1];
    float* out = (float*)d_out;
    corr_kernel<<<dim3(5120), 320, 0, stream>>>(f1, f2, out);
}

// Round 20
// 224.775 us; speedup vs baseline: 1.4084x; 1.1039x over previous
//
#include <hip/hip_runtime.h>

#define B_   8
#define C_   96
#define H_   160
#define W_   320
#define ND   9
#define NDD  81
#define TH   16
#define TW   32                 // 8 px/thread
#define KC   4                  // channels per chunk
#define NCH  24
#define F2ROWS 18
#define F2STRIDE 44             // 40 payload + 4 pad cols (2-way bank aliasing only)
#define F2PLANE (F2ROWS*F2STRIDE)   // 792 dw per channel
#define F1STRIDE 36             // 32 payload + 4 pad dw (8 payload + 1 pad seg per row)
#define F1PLANE (16*F1STRIDE)   // 576 dw per channel
#define F1O  (KC*F2PLANE)       // 3168: f1 region base within buffer
#define BUFW (KC*(F2PLANE+F1PLANE))  // 5472 dw = 21888 B per buffer
#define LDSWORDS (2*BUFW)       // 10944 dw = 43776 B -> 3 blocks/CU (9 waves),
                                // allocator target 3 w/EU -> ~170-reg budget

#define AS1 __attribute__((address_space(1)))
#define AS3 __attribute__((address_space(3)))

__device__ __forceinline__ void gld16(const float* gp, float* lp) {
    // HBM/L2 -> LDS direct; LDS dest = wave-uniform base + lane*16
    __builtin_amdgcn_global_load_lds((const AS1 float*)gp,
                                     (AS3 float*)(unsigned long long)lp, 16, 0, 0);
}

__global__ __launch_bounds__(192, 2)
void corr_kernel(const float* __restrict__ f1g,
                 const float* __restrict__ f2g,
                 float* __restrict__ out)
{
    __shared__ float lds[LDSWORDS];

    const int tid  = threadIdx.x;
    const int wave = tid >> 6;
    const int lane = tid & 63;
    const int row  = lane >> 2;         // 0..15
    const int colb = (lane & 3) << 3;   // 0,8,16,24

    // XCD swizzle: 2400 = 8 XCDs x 300 (bijective); XCD owns batch b.
    const int bid  = blockIdx.x;
    const int ebid = (bid & 7) * 300 + (bid >> 3);
    const int b    = ebid / 300;
    const int t3   = ebid - b * 300;
    const int g    = t3 % 3;            // dh = 3g + wave
    const int tile = t3 / 3;
    const int by   = tile / 10, bx = tile - by * 10;
    const int x0 = bx * TW, y0 = by * TH;
    const int HWi  = H_ * W_;
    const int r0   = y0 + 3 * g - 4;

    const float* f1b = f1g + (size_t)b * C_ * HWi;
    const float* f2b = f2g + (size_t)b * C_ * HWi;

    // ---- f2 staging maps (seg s -> lds dw 4s; r=s/11, c4=s%11; c4==10 pad) ----
    int soW, soT; bool ppW, ppT;
    {
        int s  = (wave << 6) + lane;
        int r  = s / 11, c4 = s - 11 * r;
        int gy = r0 + r, gx = x0 - 4 + (c4 << 2);
        ppW = (c4 < 10) & (gy >= 0) & (gy < H_) & (gx >= 0) & (gx <= W_ - 4);
        soW = gy * W_ + gx;
        s  = 192 + lane;
        r  = s / 11; c4 = s - 11 * r;
        gy = r0 + r; gx = x0 - 4 + (c4 << 2);
        ppT = (wave == 2) & (lane < 6) & (c4 < 10) &
              (gy >= 0) & (gy < H_) & (gx >= 0) & (gx <= W_ - 4);
        soT = gy * W_ + gx;
    }
    const int partoff = wave << 8;

    // ---- f1 staging maps: 576 segs/chunk = 3 rounds x 3 waves x 64 lanes ----
    // seg s: ch = s/144, t = s%144, frow = t/9, c = t%9 (c==8 pad, always interior)
    int f1so[3]; bool f1pp[3];
#pragma unroll
    for (int j = 0; j < 3; ++j) {
        const int s  = 192 * wave + 64 * j + lane;
        const int ch = s / 144, t = s - 144 * ch;
        const int fr = t / 9,  c = t - 9 * fr;
        f1pp[j] = (c < 8);
        f1so[j] = ch * HWi + (y0 + fr) * W_ + x0 + (c << 2);
    }

    // compute-side read bases
    const int o0   = (row + wave) * F2STRIDE + colb;   // f2
    const int f1ro = row * F1STRIDE + colb;            // f1 (per-channel plane)

    auto stage = [&](int cb, int bufb) {
#pragma unroll
        for (int c = 0; c < KC; ++c) {          // f2: 4 DMAs/wave
            const float* gsrc = f2b + (cb + c) * HWi;
            float* l = &lds[bufb + c * F2PLANE];
            if (ppW) gld16(gsrc + soW, l + partoff);
            if (ppT) gld16(gsrc + soT, l + 768);
        }
#pragma unroll
        for (int j = 0; j < 3; ++j) {           // f1: 3 DMAs/wave
            if (f1pp[j])
                gld16(f1b + cb * HWi + f1so[j],
                      &lds[bufb + F1O + (192 * wave + 64 * j) * 4]);
        }
    };

    // ---- accumulators ----
    float4 accA0, accA1, accA2, accA3, accA4, accA5, accA6, accA7, accA8;
    float4 accB0, accB1, accB2, accB3, accB4, accB5, accB6, accB7, accB8;
    accA0=accA1=accA2=accA3=accA4=accA5=accA6=accA7=accA8 = make_float4(0.f,0.f,0.f,0.f);
    accB0=accB1=accB2=accB3=accB4=accB5=accB6=accB7=accB8 = make_float4(0.f,0.f,0.f,0.f);

#define STEPD(A, P, e0, e1, e2, e3)                          \
        A.x = fmaf(P.x, e0, A.x);                            \
        A.y = fmaf(P.y, e1, A.y);                            \
        A.z = fmaf(P.z, e2, A.z);                            \
        A.w = fmaf(P.w, e3, A.w);

    // per channel: f1 frag (8 dw) + f2 window (16 dw) all from LDS
#define COMPC(c, RB) {                                                            \
        const float4 PA = *(const float4*)&lds[(RB) + F1O + c * F1PLANE + f1ro];  \
        const float4 PB = *(const float4*)&lds[(RB) + F1O + c * F1PLANE + f1ro + 4];\
        const float4 q0 = *(const float4*)&lds[(RB) + c * F2PLANE + o0];          \
        const float4 q1 = *(const float4*)&lds[(RB) + c * F2PLANE + o0 + 4];      \
        const float4 q2 = *(const float4*)&lds[(RB) + c * F2PLANE + o0 + 8];      \
        const float4 q3 = *(const float4*)&lds[(RB) + c * F2PLANE + o0 + 12];     \
        const float w[16] = {q0.x,q0.y,q0.z,q0.w,q1.x,q1.y,q1.z,q1.w,            \
                             q2.x,q2.y,q2.z,q2.w,q3.x,q3.y,q3.z,q3.w};           \
        STEPD(accA0, PA, w[0], w[1], w[2], w[3])                                  \
        STEPD(accB0, PB, w[4], w[5], w[6], w[7])                                  \
        STEPD(accA1, PA, w[1], w[2], w[3], w[4])                                  \
        STEPD(accB1, PB, w[5], w[6], w[7], w[8])                                  \
        STEPD(accA2, PA, w[2], w[3], w[4], w[5])                                  \
        STEPD(accB2, PB, w[6], w[7], w[8], w[9])                                  \
        STEPD(accA3, PA, w[3], w[4], w[5], w[6])                                  \
        STEPD(accB3, PB, w[7], w[8], w[9], w[10])                                 \
        STEPD(accA4, PA, w[4], w[5], w[6], w[7])                                  \
        STEPD(accB4, PB, w[8], w[9], w[10], w[11])                                \
        STEPD(accA5, PA, w[5], w[6], w[7], w[8])                                  \
        STEPD(accB5, PB, w[9], w[10], w[11], w[12])                               \
        STEPD(accA6, PA, w[6], w[7], w[8], w[9])                                  \
        STEPD(accB6, PB, w[10], w[11], w[12], w[13])                              \
        STEPD(accA7, PA, w[7], w[8], w[9], w[10])                                 \
        STEPD(accB7, PB, w[11], w[12], w[13], w[14])                              \
        STEPD(accA8, PA, w[8], w[9], w[10], w[11])                                \
        STEPD(accB8, PB, w[12], w[13], w[14], w[15])                              \
    }
#define CHUNK(RB) COMPC(0,RB) COMPC(1,RB) COMPC(2,RB) COMPC(3,RB)

    // one-time zero (OOB/pad slots never DMA'd; payload rewritten every chunk)
    for (int t = tid; t < LDSWORDS; t += 192) lds[t] = 0.f;
    __syncthreads();
    stage(0, 0);                          // chunk 0 (f2 + f1) -> buf 0

#pragma unroll 1
    for (int k = 0; k < NCH; ++k) {
        __syncthreads();                  // chunk-k DMA drained (issued 1 chunk ago)
        if (k + 1 < NCH) stage(KC * (k + 1), ((k + 1) & 1) * BUFW);
        __builtin_amdgcn_sched_barrier(0);  // pin DMA issue before compute
        CHUNK((k & 1) * BUFW)
    }

    // ---- epilogue: dh = 3g + wave; out[b, dh*9+d, y0+row, x0+colb..+7] ----
    const int dh = 3 * g + wave;
    const int gy = y0 + row;
    const int gx = x0 + colb;
#define STORED(d) {                                                                 \
        float* op_ = out + (size_t)((b * NDD + dh * ND + d) * H_ + gy) * W_ + gx;   \
        *(float4*)op_ = accA##d;                                                    \
        *(float4*)(op_ + 4) = accB##d; }
    STORED(0) STORED(1) STORED(2) STORED(3) STORED(4)
    STORED(5) STORED(6) STORED(7) STORED(8)
}

extern "C" void kernel_launch(void* const* d_in, const int* in_sizes, int n_in,
                              void* d_out, int out_size, void* d_ws, size_t ws_size,
                              hipStream_t stream)
{
    const float* f1 = (const float*)d_in[0];
    const float* f2 = (const float*)d_in[1];
    float* out = (float*)d_out;
    corr_kernel<<<dim3(2400), 192, 0, stream>>>(f1, f2, out);
}